// Round 15
// baseline (104.476 us; speedup 1.0000x reference)
//
#include <hip/hip_runtime.h>

#define N_NODES 100000
#define NP 100096            // NB*128 padded node count
#define N_EDGES 3200000
#define NB 782               // buckets of 128 nodes
#define NBP 1024             // padded bins for scan
#define NHR 400              // binning blocks / regions
#define EPB (N_EDGES / NHR)  // 8000 edges per region (exact, mult of 4)
#define RS 10368             // region stride (words): 8000 + 3*782 = 10346 max
#define BSB 512              // binning block threads
#define SPLIT 8              // region-split factor; split sp <-> regions r%8==sp
#define RPB (NHR / SPLIT)    // 50 regions per consumer block
#define BSC 256              // consumer block threads: 16 groups x 16 lanes
#define NG 16                // groups per consumer block
#define NWG (NB * SPLIT)     // 6256 consumer blocks = 8 * 782 (exact)
#define CHUNK (NWG / 8)      // 782 logical blocks per XCD (== NB -> sp == xcd)
#define SENT 128u            // sentinel: low byte 128 (pad slot), src=0

typedef unsigned char u8;

// Physical XCD id; placement-truth for picking the local replica. Correct
// regardless of dispatch mapping (all replicas identical).
__device__ __forceinline__ unsigned get_xcc_id() {
    unsigned x;
    asm volatile("s_getreg_b32 %0, hwreg(HW_REG_XCC_ID)" : "=s"(x));
    return x & 7u;
}

// XCD-chunked swizzle: phys%8 = XCD; XCD k owns logical [k*CHUNK,(k+1)*CHUNK).
// CHUNK==NB  =>  sp == phys&7 (consumer split sp runs on XCD sp).
__device__ __forceinline__ void decode_bs(unsigned phys, int& b, int& sp) {
    unsigned L = (phys & 7u) * CHUNK + (phys >> 3);
    sp = (int)(L / NB);
    b  = (int)(L - (unsigned)sp * NB);
}

// ---------- binning: per-block LDS counting sort, padded runs, linear flush ----
__global__ __launch_bounds__(BSB) void k_bin3(const int* __restrict__ src,
                                              const int* __restrict__ dst,
                                              unsigned* __restrict__ binned,
                                              u8* __restrict__ binned_b,
                                              unsigned* __restrict__ runinfoT) {
    __shared__ int hist[NBP];
    __shared__ int scanv[NBP];
    __shared__ int sh[BSB];
    __shared__ alignas(16) unsigned stage[RS];
    int t = threadIdx.x, blk = blockIdx.x;
    for (int i = t; i < NBP; i += BSB) hist[i] = 0;
    for (int i = t; i < RS; i += BSB) stage[i] = SENT;
    __syncthreads();
    int base = blk * EPB;
    for (int i = t * 4; i < EPB; i += BSB * 4) {
        int4 d = *(const int4*)(dst + base + i);
        atomicAdd(&hist[d.x >> 7], 1);
        atomicAdd(&hist[d.y >> 7], 1);
        atomicAdd(&hist[d.z >> 7], 1);
        atomicAdd(&hist[d.w >> 7], 1);
    }
    __syncthreads();
    int c0 = hist[2 * t], c1 = hist[2 * t + 1];
    int p0 = (c0 + 3) & ~3, p1 = (c1 + 3) & ~3;
    int v = p0 + p1;
    sh[t] = v;
    __syncthreads();
    for (int off = 1; off < BSB; off <<= 1) {
        int u = (t >= off) ? sh[t - off] : 0;
        __syncthreads();
        sh[t] += u;
        __syncthreads();
    }
    int excl = sh[t] - v;
    scanv[2 * t] = excl;
    scanv[2 * t + 1] = excl + p0;
    __syncthreads();
    for (int b = t; b < NB; b += BSB)
        runinfoT[(size_t)b * NHR + blk] =
            (unsigned)scanv[b] | ((unsigned)((hist[b] + 3) >> 2) << 16);
    __syncthreads();
    for (int i = t * 4; i < EPB; i += BSB * 4) {
        int4 s4 = *(const int4*)(src + base + i);
        int4 d4 = *(const int4*)(dst + base + i);
        int p;
        p = atomicAdd(&scanv[d4.x >> 7], 1);
        stage[p] = ((unsigned)s4.x << 8) | (unsigned)(d4.x & 127);
        p = atomicAdd(&scanv[d4.y >> 7], 1);
        stage[p] = ((unsigned)s4.y << 8) | (unsigned)(d4.y & 127);
        p = atomicAdd(&scanv[d4.z >> 7], 1);
        stage[p] = ((unsigned)s4.z << 8) | (unsigned)(d4.z & 127);
        p = atomicAdd(&scanv[d4.w >> 7], 1);
        stage[p] = ((unsigned)s4.w << 8) | (unsigned)(d4.w & 127);
    }
    __syncthreads();
    for (int i = t * 4; i < RS; i += BSB * 4) {
        *(int4*)(binned + (size_t)blk * RS + i) = *(const int4*)(stage + i);
        uchar4 w = make_uchar4((u8)(stage[i] & 255), (u8)(stage[i + 1] & 255),
                               (u8)(stage[i + 2] & 255), (u8)(stage[i + 3] & 255));
        *(uchar4*)(binned_b + (size_t)blk * RS + i) = w;
    }
}

// ---------- pass 1: partial degree (byte quads; regions r = sp + 8*rr) ----------
__global__ __launch_bounds__(BSC) void k_degP(const u8* __restrict__ binned_b,
                                              const unsigned* __restrict__ runinfoT,
                                              int* __restrict__ degP) {
    __shared__ int cnt[8][136];
    __shared__ unsigned rinfo[RPB];
    int t = threadIdx.x;
    int b, sp;
    decode_bs(blockIdx.x, b, sp);
    for (int i = t; i < 8 * 136; i += BSC) ((int*)cnt)[i] = 0;
    if (t < RPB) rinfo[t] = runinfoT[(size_t)b * NHR + sp + SPLIT * t];
    __syncthreads();
    int g = t >> 4, lane = t & 15, rep = g & 7;
    for (int rr = g; rr < RPB; rr += NG) {
        unsigned ri = rinfo[rr];
        int off = (int)(ri & 0xFFFFu), nq = (int)(ri >> 16);
        int rg = sp + SPLIT * rr;
        const uchar4* p = (const uchar4*)(binned_b + (size_t)rg * RS + off);
        for (int j = lane; j < nq; j += 16) {
            uchar4 w = p[j];
            if (w.x != 128) atomicAdd(&cnt[rep][w.x], 1);
            if (w.y != 128) atomicAdd(&cnt[rep][w.y], 1);
            if (w.z != 128) atomicAdd(&cnt[rep][w.z], 1);
            if (w.w != 128) atomicAdd(&cnt[rep][w.w], 1);
        }
    }
    __syncthreads();
    if (t < 128) {
        int d = 0;
#pragma unroll
        for (int c = 0; c < 8; ++c) d += cnt[c][t];
        degP[(size_t)sp * NP + b * 128 + t] = d;
    }
}

// ---------- node pass 1: dinv, s (nrep copies of s) ----------
__global__ __launch_bounds__(256) void k_node1(const int* __restrict__ degP,
                                               const float* __restrict__ x,
                                               float* __restrict__ dinv,
                                               float* __restrict__ s, int nrep) {
    int v = blockIdx.x * 256 + threadIdx.x;
    if (v >= N_NODES) return;
    int d = 1;
#pragma unroll
    for (int c = 0; c < SPLIT; ++c) d += degP[(size_t)c * NP + v];
    float di = rsqrtf((float)d);
    dinv[v] = di;
    float sv = di * x[v];
    for (int c = 0; c < nrep; ++c) s[(size_t)c * NP + v] = sv;
}

// ---------- pass 2: partial scatter1 (local-XCD s replica) ----------
__global__ __launch_bounds__(BSC) void k_s1P(const unsigned* __restrict__ binned,
                                             const unsigned* __restrict__ runinfoT,
                                             const float* __restrict__ s, int nrep,
                                             float* __restrict__ aggP) {
    __shared__ float acc[8][136];
    __shared__ unsigned rinfo[RPB];
    int t = threadIdx.x;
    int b, sp;
    decode_bs(blockIdx.x, b, sp);
    for (int i = t; i < 8 * 136; i += BSC) ((float*)acc)[i] = 0.f;
    if (t < RPB) rinfo[t] = runinfoT[(size_t)b * NHR + sp + SPLIT * t];
    __syncthreads();
    const float* smy = s + (nrep == 8 ? (size_t)get_xcc_id() * NP : 0);
    int g = t >> 4, lane = t & 15, rep = g & 7;
    for (int rr = g; rr < RPB; rr += NG) {
        unsigned ri = rinfo[rr];
        int off = (int)(ri & 0xFFFFu), nw = (int)(ri >> 16) * 4;
        int rg = sp + SPLIT * rr;
        const unsigned* p = binned + (size_t)rg * RS + off;
        for (int j = lane; j < nw; j += 16) {
            unsigned w = p[j];
            if ((w & 255u) != 128u) {
                float v = smy[w >> 8];
                atomicAdd(&acc[rep][w & 255], v);
            }
        }
    }
    __syncthreads();
    if (t < 128) {
        float a = 0.f;
#pragma unroll
        for (int c = 0; c < 8; ++c) a += acc[c][t];
        aggP[(size_t)sp * NP + b * 128 + t] = a;
    }
}

// ---------- node pass 2: layer-1 MLP -> z (nrep copies) ----------
__global__ __launch_bounds__(256) void k_node2(const float* __restrict__ aggP,
                                               const float* __restrict__ dinv,
                                               const float* __restrict__ s,
                                               const float* __restrict__ W1,
                                               const float* __restrict__ b1,
                                               const float* __restrict__ W2,
                                               float2* __restrict__ z, int nrep) {
    int v = blockIdx.x * 256 + threadIdx.x;
    if (v >= N_NODES) return;
    float aggv = s[v];  // self-loop term (copy 0)
#pragma unroll
    for (int c = 0; c < SPLIT; ++c) aggv += aggP[(size_t)c * NP + v];
    float di = dinv[v];
    float a = di * aggv;
    float z0 = 0.f, z1 = 0.f;
#pragma unroll
    for (int f = 0; f < 16; ++f) {
        float h = fmaxf(a * W1[f] + b1[f], 0.f);
        z0 += h * W2[2 * f + 0];
        z1 += h * W2[2 * f + 1];
    }
    float2 zv = make_float2(di * z0, di * z1);
    for (int c = 0; c < nrep; ++c) z[(size_t)c * NP + v] = zv;
}

// ---------- pass 3: partial scatter2 (local-XCD z replica) ----------
__global__ __launch_bounds__(BSC) void k_s2P(const unsigned* __restrict__ binned,
                                             const unsigned* __restrict__ runinfoT,
                                             const float2* __restrict__ z, int nrep,
                                             float2* __restrict__ agg2P) {
    __shared__ float accx[8][136], accy[8][136];
    __shared__ unsigned rinfo[RPB];
    int t = threadIdx.x;
    int b, sp;
    decode_bs(blockIdx.x, b, sp);
    for (int i = t; i < 8 * 136; i += BSC) {
        ((float*)accx)[i] = 0.f;
        ((float*)accy)[i] = 0.f;
    }
    if (t < RPB) rinfo[t] = runinfoT[(size_t)b * NHR + sp + SPLIT * t];
    __syncthreads();
    const float2* zmy = z + (nrep == 8 ? (size_t)get_xcc_id() * NP : 0);
    int g = t >> 4, lane = t & 15, rep = g & 7;
    for (int rr = g; rr < RPB; rr += NG) {
        unsigned ri = rinfo[rr];
        int off = (int)(ri & 0xFFFFu), nw = (int)(ri >> 16) * 4;
        int rg = sp + SPLIT * rr;
        const unsigned* p = binned + (size_t)rg * RS + off;
        for (int j = lane; j < nw; j += 16) {
            unsigned w = p[j];
            if ((w & 255u) != 128u) {
                float2 zz = zmy[w >> 8];
                atomicAdd(&accx[rep][w & 255], zz.x);
                atomicAdd(&accy[rep][w & 255], zz.y);
            }
        }
    }
    __syncthreads();
    if (t < 128) {
        float ax = 0.f, ay = 0.f;
#pragma unroll
        for (int c = 0; c < 8; ++c) {
            ax += accx[c][t];
            ay += accy[c][t];
        }
        agg2P[(size_t)sp * NP + b * 128 + t] = make_float2(ax, ay);
    }
}

// ---------- node pass 3: epilogue -> out ----------
__global__ __launch_bounds__(256) void k_out(const float2* __restrict__ agg2P,
                                             const float* __restrict__ dinv,
                                             const float2* __restrict__ z,
                                             const float* __restrict__ b2,
                                             float2* __restrict__ out) {
    int v = blockIdx.x * 256 + threadIdx.x;
    if (v >= N_NODES) return;
    float2 zz = z[v];  // copy 0
    float ax = zz.x, ay = zz.y;
#pragma unroll
    for (int c = 0; c < SPLIT; ++c) {
        float2 a = agg2P[(size_t)c * NP + v];
        ax += a.x;
        ay += a.y;
    }
    float di = dinv[v];
    out[v] = make_float2(di * ax + b2[0], di * ay + b2[1]);
}

// ---------- fallback (device atomics), used only if ws too small ----------
__global__ void f_deg(const int* __restrict__ dst, int* __restrict__ deg) {
    int i = blockIdx.x * blockDim.x + threadIdx.x;
    if (i < N_EDGES) atomicAdd(&deg[dst[i]], 1);
}
__global__ void f_node1(const float* __restrict__ x, const int* __restrict__ deg,
                        float* __restrict__ dinv, float* __restrict__ s) {
    int v = blockIdx.x * blockDim.x + threadIdx.x;
    if (v < N_NODES) {
        float di = rsqrtf((float)(deg[v] + 1));
        dinv[v] = di;
        s[v] = di * x[v];
    }
}
__global__ void f_scatter1(const int* __restrict__ src, const int* __restrict__ dst,
                           const float* __restrict__ s, float* __restrict__ agg1) {
    int i = blockIdx.x * blockDim.x + threadIdx.x;
    if (i < N_EDGES) atomicAdd(&agg1[dst[i]], s[src[i]]);
}
__global__ void f_node2(const float* __restrict__ dinv, const float* __restrict__ s,
                        const float* __restrict__ agg1, const float* __restrict__ W1,
                        const float* __restrict__ b1, const float* __restrict__ W2,
                        float2* __restrict__ z) {
    int v = blockIdx.x * blockDim.x + threadIdx.x;
    if (v < N_NODES) {
        float di = dinv[v];
        float a = di * (agg1[v] + s[v]);
        float z0 = 0.f, z1 = 0.f;
#pragma unroll
        for (int f = 0; f < 16; ++f) {
            float h = fmaxf(a * W1[f] + b1[f], 0.f);
            z0 += h * W2[2 * f + 0];
            z1 += h * W2[2 * f + 1];
        }
        z[v] = make_float2(di * z0, di * z1);
    }
}
__global__ void f_scatter2(const int* __restrict__ src, const int* __restrict__ dst,
                           const float2* __restrict__ z, float* __restrict__ agg2) {
    int i = blockIdx.x * blockDim.x + threadIdx.x;
    if (i < N_EDGES) {
        float2 zz = z[src[i]];
        int d = dst[i];
        atomicAdd(&agg2[2 * d + 0], zz.x);
        atomicAdd(&agg2[2 * d + 1], zz.y);
    }
}
__global__ void f_out(const float* __restrict__ dinv, const float2* __restrict__ z,
                      const float2* __restrict__ agg2, const float* __restrict__ b2,
                      float2* __restrict__ out) {
    int v = blockIdx.x * blockDim.x + threadIdx.x;
    if (v < N_NODES) {
        float di = dinv[v];
        float2 a = agg2[v], zz = z[v];
        out[v] = make_float2(di * (a.x + zz.x) + b2[0], di * (a.y + zz.y) + b2[1]);
    }
}

// ---------- launch ----------
extern "C" void kernel_launch(void* const* d_in, const int* in_sizes, int n_in,
                              void* d_out, int out_size, void* d_ws, size_t ws_size,
                              hipStream_t stream) {
    const float* x  = (const float*)d_in[0];
    const int* eidx = (const int*)d_in[1];
    const float* W1 = (const float*)d_in[2];
    const float* b1 = (const float*)d_in[3];
    const float* W2 = (const float*)d_in[4];
    const float* b2 = (const float*)d_in[5];
    float* out = (float*)d_out;

    const int n = N_NODES;
    const int* src = eidx;
    const int* dst = eidx + N_EDGES;

    // words layout: runinfoT | binned | binned_b | degP | aggP | agg2P | dinv |
    //               s[nrep*NP] | z[2*nrep*NP]
    size_t oRun   = 0;
    size_t oBin   = oRun + (size_t)NB * NHR;
    size_t oBinB  = oBin + (size_t)NHR * RS;
    size_t oDegP  = oBinB + (size_t)NHR * RS / 4;
    size_t oAggP  = oDegP + (size_t)SPLIT * NP;
    size_t oAgg2P = oAggP + (size_t)SPLIT * NP;
    size_t oDinv  = oAgg2P + (size_t)2 * SPLIT * NP;
    size_t oS     = oDinv + NP;
    size_t fixed  = oS;  // words before s
    size_t need8  = (fixed + (size_t)8 * NP + (size_t)16 * NP) * sizeof(int);
    size_t need1  = (fixed + (size_t)1 * NP + (size_t)2 * NP) * sizeof(int);

    if (ws_size >= need1) {
        int nrep = (ws_size >= need8) ? 8 : 1;
        size_t oZ = oS + (size_t)nrep * NP;
        int* wsI = (int*)d_ws;
        unsigned* runinfoT = (unsigned*)(wsI + oRun);
        unsigned* binned   = (unsigned*)(wsI + oBin);
        u8* binned_b       = (u8*)(wsI + oBinB);
        int*   degP  = wsI + oDegP;
        float* aggP  = (float*)(wsI + oAggP);
        float2* agg2P = (float2*)(wsI + oAgg2P);
        float* dinv = (float*)(wsI + oDinv);
        float* s    = (float*)(wsI + oS);
        float2* z   = (float2*)(wsI + oZ);

        k_bin3<<<NHR, BSB, 0, stream>>>(src, dst, binned, binned_b, runinfoT);
        k_degP<<<NWG, BSC, 0, stream>>>(binned_b, runinfoT, degP);
        k_node1<<<NP / 256, 256, 0, stream>>>(degP, x, dinv, s, nrep);
        k_s1P<<<NWG, BSC, 0, stream>>>(binned, runinfoT, s, nrep, aggP);
        k_node2<<<NP / 256, 256, 0, stream>>>(aggP, dinv, s, W1, b1, W2, z, nrep);
        k_s2P<<<NWG, BSC, 0, stream>>>(binned, runinfoT, z, nrep, agg2P);
        k_out<<<NP / 256, 256, 0, stream>>>(agg2P, dinv, z, b2, (float2*)out);
    } else {
        float* ws = (float*)d_ws;
        int* deg    = (int*)ws;
        float* agg1 = ws + n;
        float* agg2 = ws + 2 * n;
        float* dinv = ws + 4 * n;
        float* s    = ws + 5 * n;
        float* z    = ws + 6 * n;
        (void)hipMemsetAsync(d_ws, 0, (size_t)(4 * n) * sizeof(float), stream);
        const int gridE = (N_EDGES + 255) / 256;
        const int gridN = (n + 255) / 256;
        f_deg<<<gridE, 256, 0, stream>>>(dst, deg);
        f_node1<<<gridN, 256, 0, stream>>>(x, deg, dinv, s);
        f_scatter1<<<gridE, 256, 0, stream>>>(src, dst, s, agg1);
        f_node2<<<gridN, 256, 0, stream>>>(dinv, s, agg1, W1, b1, W2, (float2*)z);
        f_scatter2<<<gridE, 256, 0, stream>>>(src, dst, (const float2*)z, agg2);
        f_out<<<gridN, 256, 0, stream>>>(dinv, (const float2*)z, (const float2*)agg2,
                                         b2, (float2*)out);
    }
}

// Round 16
// 99.402 us; speedup vs baseline: 1.0510x; 1.0510x over previous
//
#include <hip/hip_runtime.h>

#define N_NODES 100000
#define NP 100096            // NB*128 padded node count
#define N_EDGES 3200000
#define NB 782               // buckets of 128 nodes
#define NBP 1024             // padded bins for scan
#define NHR 400              // binning blocks / regions
#define EPB (N_EDGES / NHR)  // 8000 edges per region (exact, mult of 4)
#define RS 10368             // region stride (words): 8000 + 3*782 = 10346 max
#define BSB 512              // binning block threads
#define SPLIT 8              // region-split factor; split sp <-> regions r%8==sp
#define RPB (NHR / SPLIT)    // 50 regions per consumer block
#define BSC 256              // consumer block threads: 64 groups x 4 lanes
#define NWG (NB * SPLIT)     // 6256 consumer blocks = 8 * 782 (exact)
#define CHUNK (NWG / 8)      // 782 logical blocks per XCD (== NB -> sp == xcd)
#define SENT 128u            // sentinel: low byte 128 (pad slot), src=0

typedef unsigned char u8;

// XCD-chunked swizzle: phys%8 = XCD; XCD k owns logical [k*CHUNK,(k+1)*CHUNK).
__device__ __forceinline__ void decode_bs(unsigned phys, int& b, int& sp) {
    unsigned L = (phys & 7u) * CHUNK + (phys >> 3);
    sp = (int)(L / NB);
    b  = (int)(L - (unsigned)sp * NB);
}

// ---------- binning: per-block LDS counting sort, padded runs, linear flush ----
__global__ __launch_bounds__(BSB) void k_bin3(const int* __restrict__ src,
                                              const int* __restrict__ dst,
                                              unsigned* __restrict__ binned,
                                              u8* __restrict__ binned_b,
                                              unsigned* __restrict__ runinfoT) {
    __shared__ int hist[NBP];
    __shared__ int scanv[NBP];
    __shared__ int sh[BSB];
    __shared__ alignas(16) unsigned stage[RS];
    int t = threadIdx.x, blk = blockIdx.x;
    for (int i = t; i < NBP; i += BSB) hist[i] = 0;
    for (int i = t; i < RS; i += BSB) stage[i] = SENT;
    __syncthreads();
    int base = blk * EPB;
    for (int i = t * 4; i < EPB; i += BSB * 4) {
        int4 d = *(const int4*)(dst + base + i);
        atomicAdd(&hist[d.x >> 7], 1);
        atomicAdd(&hist[d.y >> 7], 1);
        atomicAdd(&hist[d.z >> 7], 1);
        atomicAdd(&hist[d.w >> 7], 1);
    }
    __syncthreads();
    int c0 = hist[2 * t], c1 = hist[2 * t + 1];
    int p0 = (c0 + 3) & ~3, p1 = (c1 + 3) & ~3;
    int v = p0 + p1;
    sh[t] = v;
    __syncthreads();
    for (int off = 1; off < BSB; off <<= 1) {
        int u = (t >= off) ? sh[t - off] : 0;
        __syncthreads();
        sh[t] += u;
        __syncthreads();
    }
    int excl = sh[t] - v;
    scanv[2 * t] = excl;
    scanv[2 * t + 1] = excl + p0;
    __syncthreads();
    for (int b = t; b < NB; b += BSB)
        runinfoT[(size_t)b * NHR + blk] =
            (unsigned)scanv[b] | ((unsigned)((hist[b] + 3) >> 2) << 16);
    __syncthreads();
    for (int i = t * 4; i < EPB; i += BSB * 4) {
        int4 s4 = *(const int4*)(src + base + i);
        int4 d4 = *(const int4*)(dst + base + i);
        int p;
        p = atomicAdd(&scanv[d4.x >> 7], 1);
        stage[p] = ((unsigned)s4.x << 8) | (unsigned)(d4.x & 127);
        p = atomicAdd(&scanv[d4.y >> 7], 1);
        stage[p] = ((unsigned)s4.y << 8) | (unsigned)(d4.y & 127);
        p = atomicAdd(&scanv[d4.z >> 7], 1);
        stage[p] = ((unsigned)s4.z << 8) | (unsigned)(d4.z & 127);
        p = atomicAdd(&scanv[d4.w >> 7], 1);
        stage[p] = ((unsigned)s4.w << 8) | (unsigned)(d4.w & 127);
    }
    __syncthreads();
    for (int i = t * 4; i < RS; i += BSB * 4) {
        *(int4*)(binned + (size_t)blk * RS + i) = *(const int4*)(stage + i);
        uchar4 w = make_uchar4((u8)(stage[i] & 255), (u8)(stage[i + 1] & 255),
                               (u8)(stage[i + 2] & 255), (u8)(stage[i + 3] & 255));
        *(uchar4*)(binned_b + (size_t)blk * RS + i) = w;
    }
}

// ---------- pass 1: partial degree — 4-lane groups, uchar4/lane ----------
__global__ __launch_bounds__(BSC) void k_degP(const u8* __restrict__ binned_b,
                                              const unsigned* __restrict__ runinfoT,
                                              int* __restrict__ degP) {
    __shared__ int cnt[8][136];
    __shared__ unsigned rinfo[RPB];
    int t = threadIdx.x;
    int b, sp;
    decode_bs(blockIdx.x, b, sp);
    for (int i = t; i < 8 * 136; i += BSC) ((int*)cnt)[i] = 0;
    if (t < RPB) rinfo[t] = runinfoT[(size_t)b * NHR + sp + SPLIT * t];
    __syncthreads();
    int g = t >> 2, lane = t & 3, rep = g & 7;
    if (g < RPB) {
        unsigned ri = rinfo[g];
        int off = (int)(ri & 0xFFFFu), nq = (int)(ri >> 16);
        const uchar4* p =
            (const uchar4*)(binned_b + (size_t)(sp + SPLIT * g) * RS + off);
        for (int j = lane; j < nq; j += 4) {
            uchar4 w = p[j];
            if (w.x != 128) atomicAdd(&cnt[rep][w.x], 1);
            if (w.y != 128) atomicAdd(&cnt[rep][w.y], 1);
            if (w.z != 128) atomicAdd(&cnt[rep][w.z], 1);
            if (w.w != 128) atomicAdd(&cnt[rep][w.w], 1);
        }
    }
    __syncthreads();
    if (t < 128) {
        int d = 0;
#pragma unroll
        for (int c = 0; c < 8; ++c) d += cnt[c][t];
        degP[(size_t)sp * NP + b * 128 + t] = d;
    }
}

// ---------- node pass 1: dinv, s ----------
__global__ __launch_bounds__(256) void k_node1(const int* __restrict__ degP,
                                               const float* __restrict__ x,
                                               float* __restrict__ dinv,
                                               float* __restrict__ s) {
    int v = blockIdx.x * 256 + threadIdx.x;
    if (v >= N_NODES) return;
    int d = 1;
#pragma unroll
    for (int c = 0; c < SPLIT; ++c) d += degP[(size_t)c * NP + v];
    float di = rsqrtf((float)d);
    dinv[v] = di;
    s[v] = di * x[v];
}

// ---------- pass 2: partial scatter1 — 4-lane groups, uint4/lane ----------
__global__ __launch_bounds__(BSC) void k_s1P(const unsigned* __restrict__ binned,
                                             const unsigned* __restrict__ runinfoT,
                                             const float* __restrict__ s,
                                             float* __restrict__ aggP) {
    __shared__ float acc[8][136];
    __shared__ unsigned rinfo[RPB];
    int t = threadIdx.x;
    int b, sp;
    decode_bs(blockIdx.x, b, sp);
    for (int i = t; i < 8 * 136; i += BSC) ((float*)acc)[i] = 0.f;
    if (t < RPB) rinfo[t] = runinfoT[(size_t)b * NHR + sp + SPLIT * t];
    __syncthreads();
    int g = t >> 2, lane = t & 3, rep = g & 7;
    if (g < RPB) {
        unsigned ri = rinfo[g];
        int off = (int)(ri & 0xFFFFu), nq = (int)(ri >> 16);
        const uint4* p =
            (const uint4*)(binned + (size_t)(sp + SPLIT * g) * RS + off);
        for (int j = lane; j < nq; j += 4) {
            uint4 w = p[j];
            bool v0 = (w.x & 255u) != 128u, v1 = (w.y & 255u) != 128u;
            bool v2 = (w.z & 255u) != 128u, v3 = (w.w & 255u) != 128u;
            float f0 = 0.f, f1 = 0.f, f2 = 0.f, f3 = 0.f;
            if (v0) f0 = s[w.x >> 8];
            if (v1) f1 = s[w.y >> 8];
            if (v2) f2 = s[w.z >> 8];
            if (v3) f3 = s[w.w >> 8];
            if (v0) atomicAdd(&acc[rep][w.x & 255], f0);
            if (v1) atomicAdd(&acc[rep][w.y & 255], f1);
            if (v2) atomicAdd(&acc[rep][w.z & 255], f2);
            if (v3) atomicAdd(&acc[rep][w.w & 255], f3);
        }
    }
    __syncthreads();
    if (t < 128) {
        float a = 0.f;
#pragma unroll
        for (int c = 0; c < 8; ++c) a += acc[c][t];
        aggP[(size_t)sp * NP + b * 128 + t] = a;
    }
}

// ---------- node pass 2: layer-1 MLP -> z ----------
__global__ __launch_bounds__(256) void k_node2(const float* __restrict__ aggP,
                                               const float* __restrict__ dinv,
                                               const float* __restrict__ s,
                                               const float* __restrict__ W1,
                                               const float* __restrict__ b1,
                                               const float* __restrict__ W2,
                                               float2* __restrict__ z) {
    int v = blockIdx.x * 256 + threadIdx.x;
    if (v >= N_NODES) return;
    float aggv = s[v];  // self-loop term
#pragma unroll
    for (int c = 0; c < SPLIT; ++c) aggv += aggP[(size_t)c * NP + v];
    float di = dinv[v];
    float a = di * aggv;
    float z0 = 0.f, z1 = 0.f;
#pragma unroll
    for (int f = 0; f < 16; ++f) {
        float h = fmaxf(a * W1[f] + b1[f], 0.f);
        z0 += h * W2[2 * f + 0];
        z1 += h * W2[2 * f + 1];
    }
    z[v] = make_float2(di * z0, di * z1);
}

// ---------- pass 3: partial scatter2 — 4-lane groups, uint4/lane ----------
__global__ __launch_bounds__(BSC) void k_s2P(const unsigned* __restrict__ binned,
                                             const unsigned* __restrict__ runinfoT,
                                             const float2* __restrict__ z,
                                             float2* __restrict__ agg2P) {
    __shared__ float accx[8][136], accy[8][136];
    __shared__ unsigned rinfo[RPB];
    int t = threadIdx.x;
    int b, sp;
    decode_bs(blockIdx.x, b, sp);
    for (int i = t; i < 8 * 136; i += BSC) {
        ((float*)accx)[i] = 0.f;
        ((float*)accy)[i] = 0.f;
    }
    if (t < RPB) rinfo[t] = runinfoT[(size_t)b * NHR + sp + SPLIT * t];
    __syncthreads();
    int g = t >> 2, lane = t & 3, rep = g & 7;
    if (g < RPB) {
        unsigned ri = rinfo[g];
        int off = (int)(ri & 0xFFFFu), nq = (int)(ri >> 16);
        const uint4* p =
            (const uint4*)(binned + (size_t)(sp + SPLIT * g) * RS + off);
        for (int j = lane; j < nq; j += 4) {
            uint4 w = p[j];
            bool v0 = (w.x & 255u) != 128u, v1 = (w.y & 255u) != 128u;
            bool v2 = (w.z & 255u) != 128u, v3 = (w.w & 255u) != 128u;
            float2 z0, z1, z2, z3;
            if (v0) z0 = z[w.x >> 8];
            if (v1) z1 = z[w.y >> 8];
            if (v2) z2 = z[w.z >> 8];
            if (v3) z3 = z[w.w >> 8];
            if (v0) {
                atomicAdd(&accx[rep][w.x & 255], z0.x);
                atomicAdd(&accy[rep][w.x & 255], z0.y);
            }
            if (v1) {
                atomicAdd(&accx[rep][w.y & 255], z1.x);
                atomicAdd(&accy[rep][w.y & 255], z1.y);
            }
            if (v2) {
                atomicAdd(&accx[rep][w.z & 255], z2.x);
                atomicAdd(&accy[rep][w.z & 255], z2.y);
            }
            if (v3) {
                atomicAdd(&accx[rep][w.w & 255], z3.x);
                atomicAdd(&accy[rep][w.w & 255], z3.y);
            }
        }
    }
    __syncthreads();
    if (t < 128) {
        float ax = 0.f, ay = 0.f;
#pragma unroll
        for (int c = 0; c < 8; ++c) {
            ax += accx[c][t];
            ay += accy[c][t];
        }
        agg2P[(size_t)sp * NP + b * 128 + t] = make_float2(ax, ay);
    }
}

// ---------- node pass 3: epilogue -> out ----------
__global__ __launch_bounds__(256) void k_out(const float2* __restrict__ agg2P,
                                             const float* __restrict__ dinv,
                                             const float2* __restrict__ z,
                                             const float* __restrict__ b2,
                                             float2* __restrict__ out) {
    int v = blockIdx.x * 256 + threadIdx.x;
    if (v >= N_NODES) return;
    float2 zz = z[v];
    float ax = zz.x, ay = zz.y;
#pragma unroll
    for (int c = 0; c < SPLIT; ++c) {
        float2 a = agg2P[(size_t)c * NP + v];
        ax += a.x;
        ay += a.y;
    }
    float di = dinv[v];
    out[v] = make_float2(di * ax + b2[0], di * ay + b2[1]);
}

// ---------- fallback (device atomics), used only if ws too small ----------
__global__ void f_deg(const int* __restrict__ dst, int* __restrict__ deg) {
    int i = blockIdx.x * blockDim.x + threadIdx.x;
    if (i < N_EDGES) atomicAdd(&deg[dst[i]], 1);
}
__global__ void f_node1(const float* __restrict__ x, const int* __restrict__ deg,
                        float* __restrict__ dinv, float* __restrict__ s) {
    int v = blockIdx.x * blockDim.x + threadIdx.x;
    if (v < N_NODES) {
        float di = rsqrtf((float)(deg[v] + 1));
        dinv[v] = di;
        s[v] = di * x[v];
    }
}
__global__ void f_scatter1(const int* __restrict__ src, const int* __restrict__ dst,
                           const float* __restrict__ s, float* __restrict__ agg1) {
    int i = blockIdx.x * blockDim.x + threadIdx.x;
    if (i < N_EDGES) atomicAdd(&agg1[dst[i]], s[src[i]]);
}
__global__ void f_node2(const float* __restrict__ dinv, const float* __restrict__ s,
                        const float* __restrict__ agg1, const float* __restrict__ W1,
                        const float* __restrict__ b1, const float* __restrict__ W2,
                        float2* __restrict__ z) {
    int v = blockIdx.x * blockDim.x + threadIdx.x;
    if (v < N_NODES) {
        float di = dinv[v];
        float a = di * (agg1[v] + s[v]);
        float z0 = 0.f, z1 = 0.f;
#pragma unroll
        for (int f = 0; f < 16; ++f) {
            float h = fmaxf(a * W1[f] + b1[f], 0.f);
            z0 += h * W2[2 * f + 0];
            z1 += h * W2[2 * f + 1];
        }
        z[v] = make_float2(di * z0, di * z1);
    }
}
__global__ void f_scatter2(const int* __restrict__ src, const int* __restrict__ dst,
                           const float2* __restrict__ z, float* __restrict__ agg2) {
    int i = blockIdx.x * blockDim.x + threadIdx.x;
    if (i < N_EDGES) {
        float2 zz = z[src[i]];
        int d = dst[i];
        atomicAdd(&agg2[2 * d + 0], zz.x);
        atomicAdd(&agg2[2 * d + 1], zz.y);
    }
}
__global__ void f_out(const float* __restrict__ dinv, const float2* __restrict__ z,
                      const float2* __restrict__ agg2, const float* __restrict__ b2,
                      float2* __restrict__ out) {
    int v = blockIdx.x * blockDim.x + threadIdx.x;
    if (v < N_NODES) {
        float di = dinv[v];
        float2 a = agg2[v], zz = z[v];
        out[v] = make_float2(di * (a.x + zz.x) + b2[0], di * (a.y + zz.y) + b2[1]);
    }
}

// ---------- launch ----------
extern "C" void kernel_launch(void* const* d_in, const int* in_sizes, int n_in,
                              void* d_out, int out_size, void* d_ws, size_t ws_size,
                              hipStream_t stream) {
    const float* x  = (const float*)d_in[0];
    const int* eidx = (const int*)d_in[1];
    const float* W1 = (const float*)d_in[2];
    const float* b1 = (const float*)d_in[3];
    const float* W2 = (const float*)d_in[4];
    const float* b2 = (const float*)d_in[5];
    float* out = (float*)d_out;

    const int n = N_NODES;
    const int* src = eidx;
    const int* dst = eidx + N_EDGES;

    size_t oRun   = 0;
    size_t oBin   = oRun + (size_t)NB * NHR;
    size_t oBinB  = oBin + (size_t)NHR * RS;
    size_t oDegP  = oBinB + (size_t)NHR * RS / 4;
    size_t oAggP  = oDegP + (size_t)SPLIT * NP;
    size_t oAgg2P = oAggP + (size_t)SPLIT * NP;
    size_t oDinv  = oAgg2P + (size_t)2 * SPLIT * NP;
    size_t oS     = oDinv + NP;
    size_t oZ     = oS + NP;
    size_t need   = (oZ + 2 * NP) * sizeof(int);

    if (ws_size >= need) {
        int* wsI = (int*)d_ws;
        unsigned* runinfoT = (unsigned*)(wsI + oRun);
        unsigned* binned   = (unsigned*)(wsI + oBin);
        u8* binned_b       = (u8*)(wsI + oBinB);
        int*   degP  = wsI + oDegP;
        float* aggP  = (float*)(wsI + oAggP);
        float2* agg2P = (float2*)(wsI + oAgg2P);
        float* dinv = (float*)(wsI + oDinv);
        float* s    = (float*)(wsI + oS);
        float2* z   = (float2*)(wsI + oZ);

        k_bin3<<<NHR, BSB, 0, stream>>>(src, dst, binned, binned_b, runinfoT);
        k_degP<<<NWG, BSC, 0, stream>>>(binned_b, runinfoT, degP);
        k_node1<<<NP / 256, 256, 0, stream>>>(degP, x, dinv, s);
        k_s1P<<<NWG, BSC, 0, stream>>>(binned, runinfoT, s, aggP);
        k_node2<<<NP / 256, 256, 0, stream>>>(aggP, dinv, s, W1, b1, W2, z);
        k_s2P<<<NWG, BSC, 0, stream>>>(binned, runinfoT, z, agg2P);
        k_out<<<NP / 256, 256, 0, stream>>>(agg2P, dinv, z, b2, (float2*)out);
    } else {
        float* ws = (float*)d_ws;
        int* deg    = (int*)ws;
        float* agg1 = ws + n;
        float* agg2 = ws + 2 * n;
        float* dinv = ws + 4 * n;
        float* s    = ws + 5 * n;
        float* z    = ws + 6 * n;
        (void)hipMemsetAsync(d_ws, 0, (size_t)(4 * n) * sizeof(float), stream);
        const int gridE = (N_EDGES + 255) / 256;
        const int gridN = (n + 255) / 256;
        f_deg<<<gridE, 256, 0, stream>>>(dst, deg);
        f_node1<<<gridN, 256, 0, stream>>>(x, deg, dinv, s);
        f_scatter1<<<gridE, 256, 0, stream>>>(src, dst, s, agg1);
        f_node2<<<gridN, 256, 0, stream>>>(dinv, s, agg1, W1, b1, W2, (float2*)z);
        f_scatter2<<<gridE, 256, 0, stream>>>(src, dst, (const float2*)z, agg2);
        f_out<<<gridN, 256, 0, stream>>>(dinv, (const float2*)z, (const float2*)agg2,
                                         b2, (float2*)out);
    }
}

// Round 17
// 87.198 us; speedup vs baseline: 1.1981x; 1.1399x over previous
//
#include <hip/hip_runtime.h>

#define N_NODES 100000
#define NP 100096            // NB*128 padded node count
#define N_EDGES 3200000
#define NB 782               // buckets of 128 nodes
#define NBP 1024             // padded bins for scan
#define NHR 400              // binning blocks / regions
#define EPB (N_EDGES / NHR)  // 8000 edges per region (exact, mult of 4)
#define RS 10368             // region stride (words)
#define BSB 512              // binning block threads
#define CAP 6144             // regroup stage capacity (padded words); worst ~5700
#define CAPO 5120            // regroup out capacity (valid edges); worst ~4400
#define CSRS 5120            // csr words per bucket
#define SENT 128u            // sentinel: low byte 128

typedef unsigned char u8;

// ---------- binning: per-block LDS counting sort, padded runs, linear flush ----
// binned region-major; runs 4-word aligned; pads hold SENT.
// packed = (src<<8)|(dst&127). runinfoT[b*NHR+r] = off | (nq<<16), nq quads.
__global__ __launch_bounds__(BSB) void k_bin3(const int* __restrict__ src,
                                              const int* __restrict__ dst,
                                              unsigned* __restrict__ binned,
                                              unsigned* __restrict__ runinfoT) {
    __shared__ int hist[NBP];
    __shared__ int scanv[NBP];
    __shared__ int sh[BSB];
    __shared__ alignas(16) unsigned stage[RS];
    int t = threadIdx.x, blk = blockIdx.x;
    for (int i = t; i < NBP; i += BSB) hist[i] = 0;
    for (int i = t; i < RS; i += BSB) stage[i] = SENT;
    __syncthreads();
    int base = blk * EPB;
    for (int i = t * 4; i < EPB; i += BSB * 4) {
        int4 d = *(const int4*)(dst + base + i);
        atomicAdd(&hist[d.x >> 7], 1);
        atomicAdd(&hist[d.y >> 7], 1);
        atomicAdd(&hist[d.z >> 7], 1);
        atomicAdd(&hist[d.w >> 7], 1);
    }
    __syncthreads();
    int c0 = hist[2 * t], c1 = hist[2 * t + 1];
    int p0 = (c0 + 3) & ~3, p1 = (c1 + 3) & ~3;
    int v = p0 + p1;
    sh[t] = v;
    __syncthreads();
    for (int off = 1; off < BSB; off <<= 1) {
        int u = (t >= off) ? sh[t - off] : 0;
        __syncthreads();
        sh[t] += u;
        __syncthreads();
    }
    int excl = sh[t] - v;
    scanv[2 * t] = excl;
    scanv[2 * t + 1] = excl + p0;
    __syncthreads();
    for (int b = t; b < NB; b += BSB)
        runinfoT[(size_t)b * NHR + blk] =
            (unsigned)scanv[b] | ((unsigned)((hist[b] + 3) >> 2) << 16);
    __syncthreads();
    for (int i = t * 4; i < EPB; i += BSB * 4) {
        int4 s4 = *(const int4*)(src + base + i);
        int4 d4 = *(const int4*)(dst + base + i);
        int p;
        p = atomicAdd(&scanv[d4.x >> 7], 1);
        stage[p] = ((unsigned)s4.x << 8) | (unsigned)(d4.x & 127);
        p = atomicAdd(&scanv[d4.y >> 7], 1);
        stage[p] = ((unsigned)s4.y << 8) | (unsigned)(d4.y & 127);
        p = atomicAdd(&scanv[d4.z >> 7], 1);
        stage[p] = ((unsigned)s4.z << 8) | (unsigned)(d4.z & 127);
        p = atomicAdd(&scanv[d4.w >> 7], 1);
        stage[p] = ((unsigned)s4.w << 8) | (unsigned)(d4.w & 127);
    }
    __syncthreads();
    for (int i = t * 4; i < RS; i += BSB * 4)
        *(int4*)(binned + (size_t)blk * RS + i) = *(const int4*)(stage + i);
}

// ---------- regroup: bucket -> full per-node CSR + degree + node1 fused ----------
// One block per bucket. Gathers the bucket's 400 runs into LDS, counting-sorts
// by low-7 dst, writes contiguous csr (src words) + start/len/dinv/s.
__global__ __launch_bounds__(256) void k_regroup(
        const unsigned* __restrict__ binned, const unsigned* __restrict__ runinfoT,
        const float* __restrict__ x, unsigned* __restrict__ csr,
        int* __restrict__ startv, int* __restrict__ lenv,
        float* __restrict__ dinv, float* __restrict__ s) {
    __shared__ unsigned rinfo[NHR];
    __shared__ int pref[512];
    __shared__ int sh[256];
    __shared__ alignas(16) unsigned stage[CAP];
    __shared__ unsigned outA[CAPO];
    __shared__ int cnt[128];
    __shared__ int excl[128];
    __shared__ int cur[128];
    int t = threadIdx.x, b = blockIdx.x;
    for (int r = t; r < NHR; r += 256) rinfo[r] = runinfoT[(size_t)b * NHR + r];
    if (t < 128) cnt[t] = 0;
    __syncthreads();
    // scan padded run lengths (4*nq), 512 padded entries, 2 per thread
    int v0 = (2 * t < NHR) ? 4 * (int)(rinfo[2 * t] >> 16) : 0;
    int v1 = (2 * t + 1 < NHR) ? 4 * (int)(rinfo[2 * t + 1] >> 16) : 0;
    int vv = v0 + v1;
    sh[t] = vv;
    __syncthreads();
    for (int off = 1; off < 256; off <<= 1) {
        int u = (t >= off) ? sh[t - off] : 0;
        __syncthreads();
        sh[t] += u;
        __syncthreads();
    }
    int ex = sh[t] - vv;
    pref[2 * t] = ex;
    pref[2 * t + 1] = ex + v0;
    __syncthreads();
    int padTot = sh[255];
    // cooperative copy: 4-lane groups, run r, quad j per lane
    int g = t >> 2, lane = t & 3;
    for (int r = g; r < NHR; r += 64) {
        unsigned ri = rinfo[r];
        int off = (int)(ri & 0xFFFFu), nq = (int)(ri >> 16);
        int bs = pref[r];
        if (bs + 4 * nq > CAP) continue;  // impossible-margin guard
        const uint4* p = (const uint4*)(binned + (size_t)r * RS + off);
        for (int j = lane; j < nq; j += 4) {
            uint4 w = p[j];
            *(uint4*)(&stage[bs + 4 * j]) = make_uint4(w.x, w.y, w.z, w.w);
        }
    }
    __syncthreads();
    // count valid by local node idx
    for (int i = t; i < padTot; i += 256) {
        unsigned w = stage[i];
        if ((w & 255u) != 128u) atomicAdd(&cnt[w & 127], 1);
    }
    __syncthreads();
    // scan 128 counts
    if (t < 128) sh[t] = cnt[t];
    __syncthreads();
    for (int off = 1; off < 128; off <<= 1) {
        int u = (t >= off && t < 128) ? sh[t - off] : 0;
        __syncthreads();
        if (t < 128) sh[t] += u;
        __syncthreads();
    }
    if (t < 128) {
        excl[t] = sh[t] - cnt[t];
        cur[t] = sh[t] - cnt[t];
    }
    __syncthreads();
    // scatter valid src values into node-sorted order
    for (int i = t; i < padTot; i += 256) {
        unsigned w = stage[i];
        if ((w & 255u) != 128u) {
            int pos = atomicAdd(&cur[w & 127], 1);
            if (pos < CAPO) outA[pos] = w >> 8;
        }
    }
    __syncthreads();
    int fillTot = excl[127] + cnt[127];
    if (fillTot > CAPO) fillTot = CAPO;
    for (int i = t; i < fillTot; i += 256)
        csr[(size_t)b * CSRS + i] = outA[i];
    if (t < 128) {
        int node = b * 128 + t;
        if (node < N_NODES) {
            int d = cnt[t];
            float di = rsqrtf((float)(d + 1));  // +1 self-loop
            dinv[node] = di;
            s[node] = di * x[node];
            startv[node] = b * CSRS + excl[t];
            lenv[node] = d;
        }
    }
}

// ---------- s1 + MLP fused: thread per node, CSR gather-reduce, no atomics ----
__global__ __launch_bounds__(256) void k_s1c(const unsigned* __restrict__ csr,
                                             const int* __restrict__ startv,
                                             const int* __restrict__ lenv,
                                             const float* __restrict__ dinv,
                                             const float* __restrict__ s,
                                             const float* __restrict__ W1,
                                             const float* __restrict__ b1,
                                             const float* __restrict__ W2,
                                             float2* __restrict__ z) {
    int v = blockIdx.x * 256 + threadIdx.x;
    if (v >= N_NODES) return;
    int st = startv[v], n = lenv[v];
    const unsigned* p = csr + st;
    float a0 = 0.f, a1 = 0.f, a2 = 0.f, a3 = 0.f;
    int j = 0;
    for (; j + 4 <= n; j += 4) {
        unsigned c0 = p[j], c1 = p[j + 1], c2 = p[j + 2], c3 = p[j + 3];
        float f0 = s[c0], f1 = s[c1], f2 = s[c2], f3 = s[c3];
        a0 += f0;
        a1 += f1;
        a2 += f2;
        a3 += f3;
    }
    float acc = (a0 + a1) + (a2 + a3);
    for (; j < n; ++j) acc += s[p[j]];
    float di = dinv[v];
    float a = di * (acc + s[v]);  // self-loop term
    float z0 = 0.f, z1 = 0.f;
#pragma unroll
    for (int f = 0; f < 16; ++f) {
        float h = fmaxf(a * W1[f] + b1[f], 0.f);
        z0 += h * W2[2 * f + 0];
        z1 += h * W2[2 * f + 1];
    }
    z[v] = make_float2(di * z0, di * z1);
}

// ---------- s2 + epilogue fused: thread per node, float2 gather-reduce ----------
__global__ __launch_bounds__(256) void k_s2c(const unsigned* __restrict__ csr,
                                             const int* __restrict__ startv,
                                             const int* __restrict__ lenv,
                                             const float* __restrict__ dinv,
                                             const float2* __restrict__ z,
                                             const float* __restrict__ b2,
                                             float2* __restrict__ out) {
    int v = blockIdx.x * 256 + threadIdx.x;
    if (v >= N_NODES) return;
    int st = startv[v], n = lenv[v];
    const unsigned* p = csr + st;
    float x0 = 0.f, y0 = 0.f, x1 = 0.f, y1 = 0.f;
    float x2 = 0.f, y2 = 0.f, x3 = 0.f, y3 = 0.f;
    int j = 0;
    for (; j + 4 <= n; j += 4) {
        unsigned c0 = p[j], c1 = p[j + 1], c2 = p[j + 2], c3 = p[j + 3];
        float2 f0 = z[c0], f1 = z[c1], f2 = z[c2], f3 = z[c3];
        x0 += f0.x;
        y0 += f0.y;
        x1 += f1.x;
        y1 += f1.y;
        x2 += f2.x;
        y2 += f2.y;
        x3 += f3.x;
        y3 += f3.y;
    }
    float ax = (x0 + x1) + (x2 + x3);
    float ay = (y0 + y1) + (y2 + y3);
    for (; j < n; ++j) {
        float2 f = z[p[j]];
        ax += f.x;
        ay += f.y;
    }
    float2 zz = z[v];
    float di = dinv[v];
    out[v] = make_float2(di * (ax + zz.x) + b2[0], di * (ay + zz.y) + b2[1]);
}

// ---------- fallback (device atomics), used only if ws too small ----------
__global__ void f_deg(const int* __restrict__ dst, int* __restrict__ deg) {
    int i = blockIdx.x * blockDim.x + threadIdx.x;
    if (i < N_EDGES) atomicAdd(&deg[dst[i]], 1);
}
__global__ void f_node1(const float* __restrict__ x, const int* __restrict__ deg,
                        float* __restrict__ dinv, float* __restrict__ s) {
    int v = blockIdx.x * blockDim.x + threadIdx.x;
    if (v < N_NODES) {
        float di = rsqrtf((float)(deg[v] + 1));
        dinv[v] = di;
        s[v] = di * x[v];
    }
}
__global__ void f_scatter1(const int* __restrict__ src, const int* __restrict__ dst,
                           const float* __restrict__ s, float* __restrict__ agg1) {
    int i = blockIdx.x * blockDim.x + threadIdx.x;
    if (i < N_EDGES) atomicAdd(&agg1[dst[i]], s[src[i]]);
}
__global__ void f_node2(const float* __restrict__ dinv, const float* __restrict__ s,
                        const float* __restrict__ agg1, const float* __restrict__ W1,
                        const float* __restrict__ b1, const float* __restrict__ W2,
                        float2* __restrict__ z) {
    int v = blockIdx.x * blockDim.x + threadIdx.x;
    if (v < N_NODES) {
        float di = dinv[v];
        float a = di * (agg1[v] + s[v]);
        float z0 = 0.f, z1 = 0.f;
#pragma unroll
        for (int f = 0; f < 16; ++f) {
            float h = fmaxf(a * W1[f] + b1[f], 0.f);
            z0 += h * W2[2 * f + 0];
            z1 += h * W2[2 * f + 1];
        }
        z[v] = make_float2(di * z0, di * z1);
    }
}
__global__ void f_scatter2(const int* __restrict__ src, const int* __restrict__ dst,
                           const float2* __restrict__ z, float* __restrict__ agg2) {
    int i = blockIdx.x * blockDim.x + threadIdx.x;
    if (i < N_EDGES) {
        float2 zz = z[src[i]];
        int d = dst[i];
        atomicAdd(&agg2[2 * d + 0], zz.x);
        atomicAdd(&agg2[2 * d + 1], zz.y);
    }
}
__global__ void f_out(const float* __restrict__ dinv, const float2* __restrict__ z,
                      const float2* __restrict__ agg2, const float* __restrict__ b2,
                      float2* __restrict__ out) {
    int v = blockIdx.x * blockDim.x + threadIdx.x;
    if (v < N_NODES) {
        float di = dinv[v];
        float2 a = agg2[v], zz = z[v];
        out[v] = make_float2(di * (a.x + zz.x) + b2[0], di * (a.y + zz.y) + b2[1]);
    }
}

// ---------- launch ----------
extern "C" void kernel_launch(void* const* d_in, const int* in_sizes, int n_in,
                              void* d_out, int out_size, void* d_ws, size_t ws_size,
                              hipStream_t stream) {
    const float* x  = (const float*)d_in[0];
    const int* eidx = (const int*)d_in[1];
    const float* W1 = (const float*)d_in[2];
    const float* b1 = (const float*)d_in[3];
    const float* W2 = (const float*)d_in[4];
    const float* b2 = (const float*)d_in[5];
    float* out = (float*)d_out;

    const int n = N_NODES;
    const int* src = eidx;
    const int* dst = eidx + N_EDGES;

    // words layout: runinfoT | binned | csr | start | len | dinv | s | z
    size_t oRun   = 0;
    size_t oBin   = oRun + (size_t)NB * NHR;
    size_t oCsr   = oBin + (size_t)NHR * RS;
    size_t oStart = oCsr + (size_t)NB * CSRS;
    size_t oLen   = oStart + NP;
    size_t oDinv  = oLen + NP;
    size_t oS     = oDinv + NP;
    size_t oZ     = oS + NP;
    size_t need   = (oZ + 2 * NP) * sizeof(int);

    if (ws_size >= need) {
        int* wsI = (int*)d_ws;
        unsigned* runinfoT = (unsigned*)(wsI + oRun);
        unsigned* binned   = (unsigned*)(wsI + oBin);
        unsigned* csr      = (unsigned*)(wsI + oCsr);
        int* startv = wsI + oStart;
        int* lenv   = wsI + oLen;
        float* dinv = (float*)(wsI + oDinv);
        float* s    = (float*)(wsI + oS);
        float2* z   = (float2*)(wsI + oZ);

        k_bin3<<<NHR, BSB, 0, stream>>>(src, dst, binned, runinfoT);
        k_regroup<<<NB, 256, 0, stream>>>(binned, runinfoT, x, csr, startv, lenv,
                                          dinv, s);
        k_s1c<<<NP / 256, 256, 0, stream>>>(csr, startv, lenv, dinv, s, W1, b1,
                                            W2, z);
        k_s2c<<<NP / 256, 256, 0, stream>>>(csr, startv, lenv, dinv, z, b2,
                                            (float2*)out);
    } else {
        float* ws = (float*)d_ws;
        int* deg    = (int*)ws;
        float* agg1 = ws + n;
        float* agg2 = ws + 2 * n;
        float* dinv = ws + 4 * n;
        float* s    = ws + 5 * n;
        float* z    = ws + 6 * n;
        (void)hipMemsetAsync(d_ws, 0, (size_t)(4 * n) * sizeof(float), stream);
        const int gridE = (N_EDGES + 255) / 256;
        const int gridN = (n + 255) / 256;
        f_deg<<<gridE, 256, 0, stream>>>(dst, deg);
        f_node1<<<gridN, 256, 0, stream>>>(x, deg, dinv, s);
        f_scatter1<<<gridE, 256, 0, stream>>>(src, dst, s, agg1);
        f_node2<<<gridN, 256, 0, stream>>>(dinv, s, agg1, W1, b1, W2, (float2*)z);
        f_scatter2<<<gridE, 256, 0, stream>>>(src, dst, (const float2*)z, agg2);
        f_out<<<gridN, 256, 0, stream>>>(dinv, (const float2*)z, (const float2*)agg2,
                                         b2, (float2*)out);
    }
}

// Round 18
// 83.386 us; speedup vs baseline: 1.2529x; 1.0457x over previous
//
#include <hip/hip_runtime.h>

#define N_NODES 100000
#define NP 100096            // NB*128 padded node count
#define N_EDGES 3200000
#define NB 782               // buckets of 128 nodes
#define NBP 1024             // padded bins for scan
#define NHR 400              // binning blocks / regions
#define EPB (N_EDGES / NHR)  // 8000 edges per region (exact, mult of 4)
#define RS 10368             // region stride (words)
#define BSB 512              // binning block threads
#define CAP 6144             // regroup stage capacity (padded words)
#define CAPO 5120            // regroup out capacity (quad-padded per-node segs)
#define CSRS 5120            // csr words per bucket (mult of 4)
#define SENT 128u            // run-pad sentinel: low byte 128

typedef unsigned char u8;

// ---------- binning: per-block LDS counting sort, padded runs, linear flush ----
// binned region-major; runs 4-word aligned; pads hold SENT.
// packed = (src<<8)|(dst&127). runinfoT[b*NHR+r] = off | (nq<<16), nq quads.
__global__ __launch_bounds__(BSB) void k_bin3(const int* __restrict__ src,
                                              const int* __restrict__ dst,
                                              unsigned* __restrict__ binned,
                                              unsigned* __restrict__ runinfoT) {
    __shared__ int hist[NBP];
    __shared__ int scanv[NBP];
    __shared__ int sh[BSB];
    __shared__ alignas(16) unsigned stage[RS];
    int t = threadIdx.x, blk = blockIdx.x;
    for (int i = t; i < NBP; i += BSB) hist[i] = 0;
    for (int i = t; i < RS; i += BSB) stage[i] = SENT;
    __syncthreads();
    int base = blk * EPB;
    for (int i = t * 4; i < EPB; i += BSB * 4) {
        int4 d = *(const int4*)(dst + base + i);
        atomicAdd(&hist[d.x >> 7], 1);
        atomicAdd(&hist[d.y >> 7], 1);
        atomicAdd(&hist[d.z >> 7], 1);
        atomicAdd(&hist[d.w >> 7], 1);
    }
    __syncthreads();
    int c0 = hist[2 * t], c1 = hist[2 * t + 1];
    int p0 = (c0 + 3) & ~3, p1 = (c1 + 3) & ~3;
    int v = p0 + p1;
    sh[t] = v;
    __syncthreads();
    for (int off = 1; off < BSB; off <<= 1) {
        int u = (t >= off) ? sh[t - off] : 0;
        __syncthreads();
        sh[t] += u;
        __syncthreads();
    }
    int excl = sh[t] - v;
    scanv[2 * t] = excl;
    scanv[2 * t + 1] = excl + p0;
    __syncthreads();
    for (int b = t; b < NB; b += BSB)
        runinfoT[(size_t)b * NHR + blk] =
            (unsigned)scanv[b] | ((unsigned)((hist[b] + 3) >> 2) << 16);
    __syncthreads();
    for (int i = t * 4; i < EPB; i += BSB * 4) {
        int4 s4 = *(const int4*)(src + base + i);
        int4 d4 = *(const int4*)(dst + base + i);
        int p;
        p = atomicAdd(&scanv[d4.x >> 7], 1);
        stage[p] = ((unsigned)s4.x << 8) | (unsigned)(d4.x & 127);
        p = atomicAdd(&scanv[d4.y >> 7], 1);
        stage[p] = ((unsigned)s4.y << 8) | (unsigned)(d4.y & 127);
        p = atomicAdd(&scanv[d4.z >> 7], 1);
        stage[p] = ((unsigned)s4.z << 8) | (unsigned)(d4.z & 127);
        p = atomicAdd(&scanv[d4.w >> 7], 1);
        stage[p] = ((unsigned)s4.w << 8) | (unsigned)(d4.w & 127);
    }
    __syncthreads();
    for (int i = t * 4; i < RS; i += BSB * 4)
        *(int4*)(binned + (size_t)blk * RS + i) = *(const int4*)(stage + i);
}

// ---------- regroup: bucket -> per-node QUAD-ALIGNED CSR + degree + node1 ------
// Each node's csr segment starts at a quad boundary; pad slots = 0xFFFFFFFF.
__global__ __launch_bounds__(256) void k_regroup(
        const unsigned* __restrict__ binned, const unsigned* __restrict__ runinfoT,
        const float* __restrict__ x, unsigned* __restrict__ csr,
        int* __restrict__ startv, int* __restrict__ lenv,
        float* __restrict__ dinv, float* __restrict__ s) {
    __shared__ unsigned rinfo[NHR];
    __shared__ int pref[512];
    __shared__ int sh[256];
    __shared__ alignas(16) unsigned stage[CAP];
    __shared__ unsigned outA[CAPO];
    __shared__ int cnt[128];
    __shared__ int excl4[128];
    __shared__ int cur[128];
    int t = threadIdx.x, b = blockIdx.x;
    for (int r = t; r < NHR; r += 256) rinfo[r] = runinfoT[(size_t)b * NHR + r];
    if (t < 128) cnt[t] = 0;
    for (int i = t; i < CAPO; i += 256) outA[i] = 0xFFFFFFFFu;
    __syncthreads();
    // scan padded run lengths (4*nq), 512 padded entries, 2 per thread
    int v0 = (2 * t < NHR) ? 4 * (int)(rinfo[2 * t] >> 16) : 0;
    int v1 = (2 * t + 1 < NHR) ? 4 * (int)(rinfo[2 * t + 1] >> 16) : 0;
    int vv = v0 + v1;
    sh[t] = vv;
    __syncthreads();
    for (int off = 1; off < 256; off <<= 1) {
        int u = (t >= off) ? sh[t - off] : 0;
        __syncthreads();
        sh[t] += u;
        __syncthreads();
    }
    int ex = sh[t] - vv;
    pref[2 * t] = ex;
    pref[2 * t + 1] = ex + v0;
    __syncthreads();
    int padTot = sh[255];
    // cooperative copy: 4-lane groups, run r, quad j per lane
    int g = t >> 2, lane = t & 3;
    for (int r = g; r < NHR; r += 64) {
        unsigned ri = rinfo[r];
        int off = (int)(ri & 0xFFFFu), nq = (int)(ri >> 16);
        int bs = pref[r];
        if (bs + 4 * nq > CAP) continue;  // impossible-margin guard
        const uint4* p = (const uint4*)(binned + (size_t)r * RS + off);
        for (int j = lane; j < nq; j += 4) {
            uint4 w = p[j];
            *(uint4*)(&stage[bs + 4 * j]) = make_uint4(w.x, w.y, w.z, w.w);
        }
    }
    __syncthreads();
    // count valid by local node idx
    for (int i = t; i < padTot; i += 256) {
        unsigned w = stage[i];
        if ((w & 255u) != 128u) atomicAdd(&cnt[w & 127], 1);
    }
    __syncthreads();
    // scan QUAD-PADDED counts -> quad-aligned per-node offsets
    if (t < 128) sh[t] = (cnt[t] + 3) & ~3;
    __syncthreads();
    for (int off = 1; off < 128; off <<= 1) {
        int u = (t >= off && t < 128) ? sh[t - off] : 0;
        __syncthreads();
        if (t < 128) sh[t] += u;
        __syncthreads();
    }
    if (t < 128) {
        int pc = (cnt[t] + 3) & ~3;
        excl4[t] = sh[t] - pc;
        cur[t] = sh[t] - pc;
    }
    __syncthreads();
    // scatter valid src values into node-sorted order (pads stay 0xFFFFFFFF)
    for (int i = t; i < padTot; i += 256) {
        unsigned w = stage[i];
        if ((w & 255u) != 128u) {
            int pos = atomicAdd(&cur[w & 127], 1);
            if (pos < CAPO) outA[pos] = w >> 8;
        }
    }
    __syncthreads();
    int fillTot = excl4[127] + ((cnt[127] + 3) & ~3);
    if (fillTot > CAPO) fillTot = CAPO;
    for (int i = t; i < fillTot; i += 256)
        csr[(size_t)b * CSRS + i] = outA[i];
    if (t < 128) {
        int node = b * 128 + t;
        if (node < N_NODES) {
            int d = cnt[t];
            float di = rsqrtf((float)(d + 1));  // +1 self-loop
            dinv[node] = di;
            s[node] = di * x[node];
            startv[node] = b * CSRS + excl4[t];  // quad-aligned
            lenv[node] = d;
        }
    }
}

// ---------- s1 + MLP fused: 4-lane group per node, uint4 coalesced CSR ----------
__global__ __launch_bounds__(256) void k_s1c(const unsigned* __restrict__ csr,
                                             const int* __restrict__ startv,
                                             const int* __restrict__ lenv,
                                             const float* __restrict__ dinv,
                                             const float* __restrict__ s,
                                             const float* __restrict__ W1,
                                             const float* __restrict__ b1,
                                             const float* __restrict__ W2,
                                             float2* __restrict__ z) {
    int t = threadIdx.x;
    int v = blockIdx.x * 64 + (t >> 2);
    int lane = t & 3;
    if (v >= N_NODES) return;
    int st = startv[v], d = lenv[v];
    int nq = (d + 3) >> 2;
    const uint4* p = (const uint4*)(csr + st);
    float acc = 0.f;
    for (int j = lane; j < nq; j += 4) {
        uint4 w = p[j];
        float f0 = (w.x < N_NODES) ? s[w.x] : 0.f;
        float f1 = (w.y < N_NODES) ? s[w.y] : 0.f;
        float f2 = (w.z < N_NODES) ? s[w.z] : 0.f;
        float f3 = (w.w < N_NODES) ? s[w.w] : 0.f;
        acc += (f0 + f1) + (f2 + f3);
    }
    acc += __shfl_xor(acc, 1);
    acc += __shfl_xor(acc, 2);
    if (lane == 0) {
        float di = dinv[v];
        float a = di * (acc + s[v]);  // self-loop term
        float z0 = 0.f, z1 = 0.f;
#pragma unroll
        for (int f = 0; f < 16; ++f) {
            float h = fmaxf(a * W1[f] + b1[f], 0.f);
            z0 += h * W2[2 * f + 0];
            z1 += h * W2[2 * f + 1];
        }
        z[v] = make_float2(di * z0, di * z1);
    }
}

// ---------- s2 + epilogue fused: 4-lane group per node, float2 gathers ----------
__global__ __launch_bounds__(256) void k_s2c(const unsigned* __restrict__ csr,
                                             const int* __restrict__ startv,
                                             const int* __restrict__ lenv,
                                             const float* __restrict__ dinv,
                                             const float2* __restrict__ z,
                                             const float* __restrict__ b2,
                                             float2* __restrict__ out) {
    int t = threadIdx.x;
    int v = blockIdx.x * 64 + (t >> 2);
    int lane = t & 3;
    if (v >= N_NODES) return;
    int st = startv[v], d = lenv[v];
    int nq = (d + 3) >> 2;
    const uint4* p = (const uint4*)(csr + st);
    float ax = 0.f, ay = 0.f;
    for (int j = lane; j < nq; j += 4) {
        uint4 w = p[j];
        if (w.x < N_NODES) { float2 f = z[w.x]; ax += f.x; ay += f.y; }
        if (w.y < N_NODES) { float2 f = z[w.y]; ax += f.x; ay += f.y; }
        if (w.z < N_NODES) { float2 f = z[w.z]; ax += f.x; ay += f.y; }
        if (w.w < N_NODES) { float2 f = z[w.w]; ax += f.x; ay += f.y; }
    }
    ax += __shfl_xor(ax, 1);
    ax += __shfl_xor(ax, 2);
    ay += __shfl_xor(ay, 1);
    ay += __shfl_xor(ay, 2);
    if (lane == 0) {
        float2 zz = z[v];
        float di = dinv[v];
        out[v] = make_float2(di * (ax + zz.x) + b2[0], di * (ay + zz.y) + b2[1]);
    }
}

// ---------- fallback (device atomics), used only if ws too small ----------
__global__ void f_deg(const int* __restrict__ dst, int* __restrict__ deg) {
    int i = blockIdx.x * blockDim.x + threadIdx.x;
    if (i < N_EDGES) atomicAdd(&deg[dst[i]], 1);
}
__global__ void f_node1(const float* __restrict__ x, const int* __restrict__ deg,
                        float* __restrict__ dinv, float* __restrict__ s) {
    int v = blockIdx.x * blockDim.x + threadIdx.x;
    if (v < N_NODES) {
        float di = rsqrtf((float)(deg[v] + 1));
        dinv[v] = di;
        s[v] = di * x[v];
    }
}
__global__ void f_scatter1(const int* __restrict__ src, const int* __restrict__ dst,
                           const float* __restrict__ s, float* __restrict__ agg1) {
    int i = blockIdx.x * blockDim.x + threadIdx.x;
    if (i < N_EDGES) atomicAdd(&agg1[dst[i]], s[src[i]]);
}
__global__ void f_node2(const float* __restrict__ dinv, const float* __restrict__ s,
                        const float* __restrict__ agg1, const float* __restrict__ W1,
                        const float* __restrict__ b1, const float* __restrict__ W2,
                        float2* __restrict__ z) {
    int v = blockIdx.x * blockDim.x + threadIdx.x;
    if (v < N_NODES) {
        float di = dinv[v];
        float a = di * (agg1[v] + s[v]);
        float z0 = 0.f, z1 = 0.f;
#pragma unroll
        for (int f = 0; f < 16; ++f) {
            float h = fmaxf(a * W1[f] + b1[f], 0.f);
            z0 += h * W2[2 * f + 0];
            z1 += h * W2[2 * f + 1];
        }
        z[v] = make_float2(di * z0, di * z1);
    }
}
__global__ void f_scatter2(const int* __restrict__ src, const int* __restrict__ dst,
                           const float2* __restrict__ z, float* __restrict__ agg2) {
    int i = blockIdx.x * blockDim.x + threadIdx.x;
    if (i < N_EDGES) {
        float2 zz = z[src[i]];
        int d = dst[i];
        atomicAdd(&agg2[2 * d + 0], zz.x);
        atomicAdd(&agg2[2 * d + 1], zz.y);
    }
}
__global__ void f_out(const float* __restrict__ dinv, const float2* __restrict__ z,
                      const float2* __restrict__ agg2, const float* __restrict__ b2,
                      float2* __restrict__ out) {
    int v = blockIdx.x * blockDim.x + threadIdx.x;
    if (v < N_NODES) {
        float di = dinv[v];
        float2 a = agg2[v], zz = z[v];
        out[v] = make_float2(di * (a.x + zz.x) + b2[0], di * (a.y + zz.y) + b2[1]);
    }
}

// ---------- launch ----------
extern "C" void kernel_launch(void* const* d_in, const int* in_sizes, int n_in,
                              void* d_out, int out_size, void* d_ws, size_t ws_size,
                              hipStream_t stream) {
    const float* x  = (const float*)d_in[0];
    const int* eidx = (const int*)d_in[1];
    const float* W1 = (const float*)d_in[2];
    const float* b1 = (const float*)d_in[3];
    const float* W2 = (const float*)d_in[4];
    const float* b2 = (const float*)d_in[5];
    float* out = (float*)d_out;

    const int n = N_NODES;
    const int* src = eidx;
    const int* dst = eidx + N_EDGES;

    // words layout: runinfoT | binned | csr | start | len | dinv | s | z
    size_t oRun   = 0;
    size_t oBin   = oRun + (size_t)NB * NHR;
    size_t oCsr   = oBin + (size_t)NHR * RS;
    size_t oStart = oCsr + (size_t)NB * CSRS;
    size_t oLen   = oStart + NP;
    size_t oDinv  = oLen + NP;
    size_t oS     = oDinv + NP;
    size_t oZ     = oS + NP;
    size_t need   = (oZ + 2 * NP) * sizeof(int);

    if (ws_size >= need) {
        int* wsI = (int*)d_ws;
        unsigned* runinfoT = (unsigned*)(wsI + oRun);
        unsigned* binned   = (unsigned*)(wsI + oBin);
        unsigned* csr      = (unsigned*)(wsI + oCsr);
        int* startv = wsI + oStart;
        int* lenv   = wsI + oLen;
        float* dinv = (float*)(wsI + oDinv);
        float* s    = (float*)(wsI + oS);
        float2* z   = (float2*)(wsI + oZ);

        const int gridS = (N_NODES + 63) / 64;  // 1563 blocks, 64 nodes each
        k_bin3<<<NHR, BSB, 0, stream>>>(src, dst, binned, runinfoT);
        k_regroup<<<NB, 256, 0, stream>>>(binned, runinfoT, x, csr, startv, lenv,
                                          dinv, s);
        k_s1c<<<gridS, 256, 0, stream>>>(csr, startv, lenv, dinv, s, W1, b1,
                                         W2, z);
        k_s2c<<<gridS, 256, 0, stream>>>(csr, startv, lenv, dinv, z, b2,
                                         (float2*)out);
    } else {
        float* ws = (float*)d_ws;
        int* deg    = (int*)ws;
        float* agg1 = ws + n;
        float* agg2 = ws + 2 * n;
        float* dinv = ws + 4 * n;
        float* s    = ws + 5 * n;
        float* z    = ws + 6 * n;
        (void)hipMemsetAsync(d_ws, 0, (size_t)(4 * n) * sizeof(float), stream);
        const int gridE = (N_EDGES + 255) / 256;
        const int gridN = (n + 255) / 256;
        f_deg<<<gridE, 256, 0, stream>>>(dst, deg);
        f_node1<<<gridN, 256, 0, stream>>>(x, deg, dinv, s);
        f_scatter1<<<gridE, 256, 0, stream>>>(src, dst, s, agg1);
        f_node2<<<gridN, 256, 0, stream>>>(dinv, s, agg1, W1, b1, W2, (float2*)z);
        f_scatter2<<<gridE, 256, 0, stream>>>(src, dst, (const float2*)z, agg2);
        f_out<<<gridN, 256, 0, stream>>>(dinv, (const float2*)z, (const float2*)agg2,
                                         b2, (float2*)out);
    }
}

// Round 19
// 79.863 us; speedup vs baseline: 1.3082x; 1.0441x over previous
//
#include <hip/hip_runtime.h>

#define N_NODES 100000
#define NP 100096            // NB*128 padded node count
#define N_EDGES 3200000
#define NB 782               // buckets of 128 nodes
#define NBP 1024             // padded bins for scan
#define NHR 256              // binning blocks / regions (256*12500 = 3.2M exact)
#define EPB (N_EDGES / NHR)  // 12500 edges per region (mult of 4)
#define RS 14848             // region stride (words): 12500 + 3*782 = 14846 max
#define BSB 512              // binning block threads
#define CAP 6144             // regroup stage capacity (padded words)
#define CAPO 5120            // regroup out capacity (quad-padded per-node segs)
#define CSRS 5120            // csr words per bucket (mult of 4)
#define SENT 128u            // run-pad sentinel: low byte 128

typedef unsigned char u8;

// ---------- binning: per-block LDS counting sort, padded runs, linear flush ----
// binned region-major; runs 4-word aligned; pads hold SENT.
// packed = (src<<8)|(dst&127). runinfoT[b*NHR+r] = off | (nq<<16), nq quads.
__global__ __launch_bounds__(BSB) void k_bin3(const int* __restrict__ src,
                                              const int* __restrict__ dst,
                                              unsigned* __restrict__ binned,
                                              unsigned* __restrict__ runinfoT) {
    __shared__ int hist[NBP];
    __shared__ int scanv[NBP];
    __shared__ int sh[BSB];
    __shared__ alignas(16) unsigned stage[RS];
    int t = threadIdx.x, blk = blockIdx.x;
    for (int i = t; i < NBP; i += BSB) hist[i] = 0;
    for (int i = t; i < RS; i += BSB) stage[i] = SENT;
    __syncthreads();
    int base = blk * EPB;
    for (int i = t * 4; i < EPB; i += BSB * 4) {
        int4 d = *(const int4*)(dst + base + i);
        atomicAdd(&hist[d.x >> 7], 1);
        atomicAdd(&hist[d.y >> 7], 1);
        atomicAdd(&hist[d.z >> 7], 1);
        atomicAdd(&hist[d.w >> 7], 1);
    }
    __syncthreads();
    int c0 = hist[2 * t], c1 = hist[2 * t + 1];
    int p0 = (c0 + 3) & ~3, p1 = (c1 + 3) & ~3;
    int v = p0 + p1;
    sh[t] = v;
    __syncthreads();
    for (int off = 1; off < BSB; off <<= 1) {
        int u = (t >= off) ? sh[t - off] : 0;
        __syncthreads();
        sh[t] += u;
        __syncthreads();
    }
    int excl = sh[t] - v;
    scanv[2 * t] = excl;
    scanv[2 * t + 1] = excl + p0;
    __syncthreads();
    int padTot = sh[BSB - 1];  // total padded words actually used
    for (int b = t; b < NB; b += BSB)
        runinfoT[(size_t)b * NHR + blk] =
            (unsigned)scanv[b] | ((unsigned)((hist[b] + 3) >> 2) << 16);
    __syncthreads();
    for (int i = t * 4; i < EPB; i += BSB * 4) {
        int4 s4 = *(const int4*)(src + base + i);
        int4 d4 = *(const int4*)(dst + base + i);
        int p;
        p = atomicAdd(&scanv[d4.x >> 7], 1);
        stage[p] = ((unsigned)s4.x << 8) | (unsigned)(d4.x & 127);
        p = atomicAdd(&scanv[d4.y >> 7], 1);
        stage[p] = ((unsigned)s4.y << 8) | (unsigned)(d4.y & 127);
        p = atomicAdd(&scanv[d4.z >> 7], 1);
        stage[p] = ((unsigned)s4.z << 8) | (unsigned)(d4.z & 127);
        p = atomicAdd(&scanv[d4.w >> 7], 1);
        stage[p] = ((unsigned)s4.w << 8) | (unsigned)(d4.w & 127);
    }
    __syncthreads();
    for (int i = t * 4; i < padTot; i += BSB * 4)  // flush only used words
        *(int4*)(binned + (size_t)blk * RS + i) = *(const int4*)(stage + i);
}

// ---------- regroup: bucket -> per-node QUAD-ALIGNED CSR + degree + node1 ------
// Each node's csr segment starts at a quad boundary; pad slots = 0xFFFFFFFF.
__global__ __launch_bounds__(256) void k_regroup(
        const unsigned* __restrict__ binned, const unsigned* __restrict__ runinfoT,
        const float* __restrict__ x, unsigned* __restrict__ csr,
        int* __restrict__ startv, int* __restrict__ lenv,
        float* __restrict__ dinv, float* __restrict__ s) {
    __shared__ unsigned rinfo[NHR];
    __shared__ int pref[NHR];
    __shared__ int sh[256];
    __shared__ alignas(16) unsigned stage[CAP];
    __shared__ unsigned outA[CAPO];
    __shared__ int cnt[128];
    __shared__ int excl4[128];
    __shared__ int cur[128];
    int t = threadIdx.x, b = blockIdx.x;
    rinfo[t] = runinfoT[(size_t)b * NHR + t];  // NHR == 256 == blockDim
    if (t < 128) cnt[t] = 0;
    for (int i = t; i < CAPO; i += 256) outA[i] = 0xFFFFFFFFu;
    __syncthreads();
    // scan padded run lengths (4*nq), one entry per thread
    int vv = 4 * (int)(rinfo[t] >> 16);
    sh[t] = vv;
    __syncthreads();
    for (int off = 1; off < 256; off <<= 1) {
        int u = (t >= off) ? sh[t - off] : 0;
        __syncthreads();
        sh[t] += u;
        __syncthreads();
    }
    pref[t] = sh[t] - vv;
    __syncthreads();
    int padTot = sh[255];
    // cooperative copy: 4-lane groups, run r, quad j per lane
    int g = t >> 2, lane = t & 3;
    for (int r = g; r < NHR; r += 64) {
        unsigned ri = rinfo[r];
        int off = (int)(ri & 0xFFFFu), nq = (int)(ri >> 16);
        int bs = pref[r];
        if (bs + 4 * nq > CAP) continue;  // impossible-margin guard
        const uint4* p = (const uint4*)(binned + (size_t)r * RS + off);
        for (int j = lane; j < nq; j += 4) {
            uint4 w = p[j];
            *(uint4*)(&stage[bs + 4 * j]) = make_uint4(w.x, w.y, w.z, w.w);
        }
    }
    __syncthreads();
    // count valid by local node idx
    for (int i = t; i < padTot; i += 256) {
        unsigned w = stage[i];
        if ((w & 255u) != 128u) atomicAdd(&cnt[w & 127], 1);
    }
    __syncthreads();
    // scan QUAD-PADDED counts -> quad-aligned per-node offsets
    if (t < 128) sh[t] = (cnt[t] + 3) & ~3;
    __syncthreads();
    for (int off = 1; off < 128; off <<= 1) {
        int u = (t >= off && t < 128) ? sh[t - off] : 0;
        __syncthreads();
        if (t < 128) sh[t] += u;
        __syncthreads();
    }
    if (t < 128) {
        int pc = (cnt[t] + 3) & ~3;
        excl4[t] = sh[t] - pc;
        cur[t] = sh[t] - pc;
    }
    __syncthreads();
    // scatter valid src values into node-sorted order (pads stay 0xFFFFFFFF)
    for (int i = t; i < padTot; i += 256) {
        unsigned w = stage[i];
        if ((w & 255u) != 128u) {
            int pos = atomicAdd(&cur[w & 127], 1);
            if (pos < CAPO) outA[pos] = w >> 8;
        }
    }
    __syncthreads();
    int fillTot = excl4[127] + ((cnt[127] + 3) & ~3);
    if (fillTot > CAPO) fillTot = CAPO;
    for (int i = t; i < fillTot; i += 256)
        csr[(size_t)b * CSRS + i] = outA[i];
    if (t < 128) {
        int node = b * 128 + t;
        if (node < N_NODES) {
            int d = cnt[t];
            float di = rsqrtf((float)(d + 1));  // +1 self-loop
            dinv[node] = di;
            s[node] = di * x[node];
            startv[node] = b * CSRS + excl4[t];  // quad-aligned
            lenv[node] = d;
        }
    }
}

// ---------- s1 + MLP fused: 4-lane group per node, uint4 coalesced CSR ----------
__global__ __launch_bounds__(256) void k_s1c(const unsigned* __restrict__ csr,
                                             const int* __restrict__ startv,
                                             const int* __restrict__ lenv,
                                             const float* __restrict__ dinv,
                                             const float* __restrict__ s,
                                             const float* __restrict__ W1,
                                             const float* __restrict__ b1,
                                             const float* __restrict__ W2,
                                             float2* __restrict__ z) {
    int t = threadIdx.x;
    int v = blockIdx.x * 64 + (t >> 2);
    int lane = t & 3;
    if (v >= N_NODES) return;
    int st = startv[v], d = lenv[v];
    int nq = (d + 3) >> 2;
    const uint4* p = (const uint4*)(csr + st);
    float acc = 0.f;
    for (int j = lane; j < nq; j += 4) {
        uint4 w = p[j];
        float f0 = (w.x < N_NODES) ? s[w.x] : 0.f;
        float f1 = (w.y < N_NODES) ? s[w.y] : 0.f;
        float f2 = (w.z < N_NODES) ? s[w.z] : 0.f;
        float f3 = (w.w < N_NODES) ? s[w.w] : 0.f;
        acc += (f0 + f1) + (f2 + f3);
    }
    acc += __shfl_xor(acc, 1);
    acc += __shfl_xor(acc, 2);
    if (lane == 0) {
        float di = dinv[v];
        float a = di * (acc + s[v]);  // self-loop term
        float z0 = 0.f, z1 = 0.f;
#pragma unroll
        for (int f = 0; f < 16; ++f) {
            float h = fmaxf(a * W1[f] + b1[f], 0.f);
            z0 += h * W2[2 * f + 0];
            z1 += h * W2[2 * f + 1];
        }
        z[v] = make_float2(di * z0, di * z1);
    }
}

// ---------- s2 + epilogue fused: 4-lane group per node, float2 gathers ----------
__global__ __launch_bounds__(256) void k_s2c(const unsigned* __restrict__ csr,
                                             const int* __restrict__ startv,
                                             const int* __restrict__ lenv,
                                             const float* __restrict__ dinv,
                                             const float2* __restrict__ z,
                                             const float* __restrict__ b2,
                                             float2* __restrict__ out) {
    int t = threadIdx.x;
    int v = blockIdx.x * 64 + (t >> 2);
    int lane = t & 3;
    if (v >= N_NODES) return;
    int st = startv[v], d = lenv[v];
    int nq = (d + 3) >> 2;
    const uint4* p = (const uint4*)(csr + st);
    float ax = 0.f, ay = 0.f;
    for (int j = lane; j < nq; j += 4) {
        uint4 w = p[j];
        if (w.x < N_NODES) { float2 f = z[w.x]; ax += f.x; ay += f.y; }
        if (w.y < N_NODES) { float2 f = z[w.y]; ax += f.x; ay += f.y; }
        if (w.z < N_NODES) { float2 f = z[w.z]; ax += f.x; ay += f.y; }
        if (w.w < N_NODES) { float2 f = z[w.w]; ax += f.x; ay += f.y; }
    }
    ax += __shfl_xor(ax, 1);
    ax += __shfl_xor(ax, 2);
    ay += __shfl_xor(ay, 1);
    ay += __shfl_xor(ay, 2);
    if (lane == 0) {
        float2 zz = z[v];
        float di = dinv[v];
        out[v] = make_float2(di * (ax + zz.x) + b2[0], di * (ay + zz.y) + b2[1]);
    }
}

// ---------- fallback (device atomics), used only if ws too small ----------
__global__ void f_deg(const int* __restrict__ dst, int* __restrict__ deg) {
    int i = blockIdx.x * blockDim.x + threadIdx.x;
    if (i < N_EDGES) atomicAdd(&deg[dst[i]], 1);
}
__global__ void f_node1(const float* __restrict__ x, const int* __restrict__ deg,
                        float* __restrict__ dinv, float* __restrict__ s) {
    int v = blockIdx.x * blockDim.x + threadIdx.x;
    if (v < N_NODES) {
        float di = rsqrtf((float)(deg[v] + 1));
        dinv[v] = di;
        s[v] = di * x[v];
    }
}
__global__ void f_scatter1(const int* __restrict__ src, const int* __restrict__ dst,
                           const float* __restrict__ s, float* __restrict__ agg1) {
    int i = blockIdx.x * blockDim.x + threadIdx.x;
    if (i < N_EDGES) atomicAdd(&agg1[dst[i]], s[src[i]]);
}
__global__ void f_node2(const float* __restrict__ dinv, const float* __restrict__ s,
                        const float* __restrict__ agg1, const float* __restrict__ W1,
                        const float* __restrict__ b1, const float* __restrict__ W2,
                        float2* __restrict__ z) {
    int v = blockIdx.x * blockDim.x + threadIdx.x;
    if (v < N_NODES) {
        float di = dinv[v];
        float a = di * (agg1[v] + s[v]);
        float z0 = 0.f, z1 = 0.f;
#pragma unroll
        for (int f = 0; f < 16; ++f) {
            float h = fmaxf(a * W1[f] + b1[f], 0.f);
            z0 += h * W2[2 * f + 0];
            z1 += h * W2[2 * f + 1];
        }
        z[v] = make_float2(di * z0, di * z1);
    }
}
__global__ void f_scatter2(const int* __restrict__ src, const int* __restrict__ dst,
                           const float2* __restrict__ z, float* __restrict__ agg2) {
    int i = blockIdx.x * blockDim.x + threadIdx.x;
    if (i < N_EDGES) {
        float2 zz = z[src[i]];
        int d = dst[i];
        atomicAdd(&agg2[2 * d + 0], zz.x);
        atomicAdd(&agg2[2 * d + 1], zz.y);
    }
}
__global__ void f_out(const float* __restrict__ dinv, const float2* __restrict__ z,
                      const float2* __restrict__ agg2, const float* __restrict__ b2,
                      float2* __restrict__ out) {
    int v = blockIdx.x * blockDim.x + threadIdx.x;
    if (v < N_NODES) {
        float di = dinv[v];
        float2 a = agg2[v], zz = z[v];
        out[v] = make_float2(di * (a.x + zz.x) + b2[0], di * (a.y + zz.y) + b2[1]);
    }
}

// ---------- launch ----------
extern "C" void kernel_launch(void* const* d_in, const int* in_sizes, int n_in,
                              void* d_out, int out_size, void* d_ws, size_t ws_size,
                              hipStream_t stream) {
    const float* x  = (const float*)d_in[0];
    const int* eidx = (const int*)d_in[1];
    const float* W1 = (const float*)d_in[2];
    const float* b1 = (const float*)d_in[3];
    const float* W2 = (const float*)d_in[4];
    const float* b2 = (const float*)d_in[5];
    float* out = (float*)d_out;

    const int n = N_NODES;
    const int* src = eidx;
    const int* dst = eidx + N_EDGES;

    // words layout: runinfoT | binned | csr | start | len | dinv | s | z
    size_t oRun   = 0;
    size_t oBin   = oRun + (size_t)NB * NHR;
    size_t oCsr   = oBin + (size_t)NHR * RS;
    size_t oStart = oCsr + (size_t)NB * CSRS;
    size_t oLen   = oStart + NP;
    size_t oDinv  = oLen + NP;
    size_t oS     = oDinv + NP;
    size_t oZ     = oS + NP;
    size_t need   = (oZ + 2 * NP) * sizeof(int);

    if (ws_size >= need) {
        int* wsI = (int*)d_ws;
        unsigned* runinfoT = (unsigned*)(wsI + oRun);
        unsigned* binned   = (unsigned*)(wsI + oBin);
        unsigned* csr      = (unsigned*)(wsI + oCsr);
        int* startv = wsI + oStart;
        int* lenv   = wsI + oLen;
        float* dinv = (float*)(wsI + oDinv);
        float* s    = (float*)(wsI + oS);
        float2* z   = (float2*)(wsI + oZ);

        const int gridS = (N_NODES + 63) / 64;  // 1563 blocks, 64 nodes each
        k_bin3<<<NHR, BSB, 0, stream>>>(src, dst, binned, runinfoT);
        k_regroup<<<NB, 256, 0, stream>>>(binned, runinfoT, x, csr, startv, lenv,
                                          dinv, s);
        k_s1c<<<gridS, 256, 0, stream>>>(csr, startv, lenv, dinv, s, W1, b1,
                                         W2, z);
        k_s2c<<<gridS, 256, 0, stream>>>(csr, startv, lenv, dinv, z, b2,
                                         (float2*)out);
    } else {
        float* ws = (float*)d_ws;
        int* deg    = (int*)ws;
        float* agg1 = ws + n;
        float* agg2 = ws + 2 * n;
        float* dinv = ws + 4 * n;
        float* s    = ws + 5 * n;
        float* z    = ws + 6 * n;
        (void)hipMemsetAsync(d_ws, 0, (size_t)(4 * n) * sizeof(float), stream);
        const int gridE = (N_EDGES + 255) / 256;
        const int gridN = (n + 255) / 256;
        f_deg<<<gridE, 256, 0, stream>>>(dst, deg);
        f_node1<<<gridN, 256, 0, stream>>>(x, deg, dinv, s);
        f_scatter1<<<gridE, 256, 0, stream>>>(src, dst, s, agg1);
        f_node2<<<gridN, 256, 0, stream>>>(dinv, s, agg1, W1, b1, W2, (float2*)z);
        f_scatter2<<<gridE, 256, 0, stream>>>(src, dst, (const float2*)z, agg2);
        f_out<<<gridN, 256, 0, stream>>>(dinv, (const float2*)z, (const float2*)agg2,
                                         b2, (float2*)out);
    }
}